// Round 5
// baseline (294.458 us; speedup 1.0000x reference)
//
#include <hip/hip_runtime.h>
#include <cstdint>
#include <cstddef>

#define WS 64
#define SHIFT 32
#define WTOT 8192
#define NWIN 128
#define SCALE_F 0.125f
#define LSTR 72        // padded LDS row stride (elems): 144 B, 16B-aligned
#define WPB 8          // windows per block
#define NBLK 512       // 4096 / WPB

typedef __bf16 bf16x8 __attribute__((ext_vector_type(8)));
typedef unsigned short u16x8 __attribute__((ext_vector_type(8)));
typedef unsigned short u16x4 __attribute__((ext_vector_type(4)));
typedef float f32x4 __attribute__((ext_vector_type(4)));

// Truncation split for Q/K (hi+lo used, combined error ~2^-16 relative).
__device__ __forceinline__ void split1(float f, unsigned short& h, unsigned short& l) {
  const unsigned u = __builtin_bit_cast(unsigned, f);
  h = (unsigned short)(u >> 16);
  const float hf = __builtin_bit_cast(float, u & 0xFFFF0000u);
  const float r = f - hf;
  l = (unsigned short)(__builtin_bit_cast(unsigned, r) >> 16);
}

__device__ __forceinline__ void split8(const float* f, bf16x8& hi, bf16x8& lo) {
  u16x8 hv, lv;
#pragma unroll
  for (int e = 0; e < 8; ++e) {
    unsigned short hh, ll;
    split1(f[e], hh, ll);
    hv[e] = hh; lv[e] = ll;
  }
  hi = __builtin_bit_cast(bf16x8, hv);
  lo = __builtin_bit_cast(bf16x8, lv);
}

// RNE bf16 for V and P (errors enter linearly through the convex PV average).
__device__ __forceinline__ unsigned short rne1(float f) {
  unsigned u = __builtin_bit_cast(unsigned, f);
  u += 0x7FFFu + ((u >> 16) & 1u);
  return (unsigned short)(u >> 16);
}
__device__ __forceinline__ float bf2f(unsigned short h) {
  return __builtin_bit_cast(float, ((unsigned)h) << 16);
}

// Barrier WITHOUT vmcnt drain (CK block_sync_lds idiom): LDS writes are made
// visible (lgkmcnt(0)) but in-flight global prefetch loads stay outstanding.
__device__ __forceinline__ void lds_barrier() {
  asm volatile("s_waitcnt lgkmcnt(0)\n\ts_barrier" ::: "memory");
}

// 512 blocks x 256 threads; each block pipelines 8 consecutive windows:
// window i+1's global loads are issued before window i's compute begins and
// stay in flight across all (vmcnt-free) phase barriers.
__global__ __launch_bounds__(256, 2) void win_attn(
    const float* __restrict__ q, const float* __restrict__ k,
    const float* __restrict__ v, const float* __restrict__ table,
    float* __restrict__ xout, float* __restrict__ attn_out) {
  __shared__ __align__(16) unsigned short s_k[2][WS * LSTR];  // K hi/lo -> P -> x-bounce
  __shared__ __align__(16) unsigned short s_vt[WS * LSTR];    // V^T (RNE bf16)
  __shared__ float s_bias[2 * WS - 1];

  const int t = threadIdx.x;
  const int lane = t & 63;
  const int wave = t >> 6;
  const int lrow = lane & 15;
  const int quad = lane >> 4;
  const int srow = t >> 4;          // staging sub-row 0..15
  const int scol = (t & 15) << 2;   // staging col 0,4,..,60

  if (t < 2 * WS - 1) s_bias[t] = table[t];

  // ---- issue all 12 float4 loads for one window (fully coalesced) ----
  auto issue = [&](int idx, float4* L) {
    const int batch = idx >> 7;
    const int win = idx & (NWIN - 1);
    const size_t tb = (size_t)batch * WTOT;
    // Q: own-wave fragment rows (L1 absorbs the segment scatter)
    const int gq = (win * WS + wave * 16 + lrow + SHIFT) & (WTOT - 1);
    const float* qp = q + (tb + gq) * WS + quad * 8;
    L[0] = *(const float4*)(qp);
    L[1] = *(const float4*)(qp + 4);
    L[2] = *(const float4*)(qp + 32);
    L[3] = *(const float4*)(qp + 36);
    // K/V: chunked linear map -> each instr is 1KB contiguous per wave
#pragma unroll
    for (int c = 0; c < 4; ++c) {
      const int row = c * 16 + srow;
      const int gr = (win * WS + row + SHIFT) & (WTOT - 1);
      const size_t base = (tb + gr) * WS + scol;
      L[4 + c] = *(const float4*)(k + base);
      L[8 + c] = *(const float4*)(v + base);
    }
  };

  // ---- full per-window processing ----
  auto process = [&](int idx, const float4* L) {
    const int batch = idx >> 7;
    const int win = idx & (NWIN - 1);
    const bool masked = (win == NWIN - 1);

    // staging: K hi/lo (packed b64) + V^T into LDS
#pragma unroll
    for (int c = 0; c < 4; ++c) {
      const int row = c * 16 + srow;
      const float4 kf = L[4 + c];
      const float ka[4] = {kf.x, kf.y, kf.z, kf.w};
      u16x4 h4, l4;
#pragma unroll
      for (int e = 0; e < 4; ++e) {
        unsigned short h, l;
        split1(ka[e], h, l);
        h4[e] = h; l4[e] = l;
      }
      *(u16x4*)(&s_k[0][row * LSTR + scol]) = h4;
      *(u16x4*)(&s_k[1][row * LSTR + scol]) = l4;
      const float4 vf = L[8 + c];
      const float va[4] = {vf.x, vf.y, vf.z, vf.w};
#pragma unroll
      for (int e = 0; e < 4; ++e)
        s_vt[(scol + e) * LSTR + row] = rne1(va[e]);
    }
    // Q fragments in registers (hi/lo split)
    bf16x8 aq_hi[2], aq_lo[2];
#pragma unroll
    for (int kh = 0; kh < 2; ++kh) {
      const float4 f0 = L[2 * kh], f1 = L[2 * kh + 1];
      const float fa[8] = {f0.x, f0.y, f0.z, f0.w, f1.x, f1.y, f1.z, f1.w};
      split8(fa, aq_hi[kh], aq_lo[kh]);
    }
    lds_barrier();  // (1) staging visible

    // S = Q K^T (split-bf16, 3 MFMA per tile)
    const f32x4 z4 = {0.f, 0.f, 0.f, 0.f};
    f32x4 acc[4] = {z4, z4, z4, z4};
#pragma unroll
    for (int kh = 0; kh < 2; ++kh) {
      const int k0 = kh * 32 + quad * 8;
#pragma unroll
      for (int j = 0; j < 4; ++j) {
        const bf16x8 bhi = *(const bf16x8*)(&s_k[0][(j * 16 + lrow) * LSTR + k0]);
        const bf16x8 blo = *(const bf16x8*)(&s_k[1][(j * 16 + lrow) * LSTR + k0]);
        acc[j] = __builtin_amdgcn_mfma_f32_16x16x32_bf16(aq_hi[kh], bhi, acc[j], 0, 0, 0);
        acc[j] = __builtin_amdgcn_mfma_f32_16x16x32_bf16(aq_lo[kh], bhi, acc[j], 0, 0, 0);
        acc[j] = __builtin_amdgcn_mfma_f32_16x16x32_bf16(aq_hi[kh], blo, acc[j], 0, 0, 0);
      }
    }

    // softmax in registers (row = 16 lanes of one quad)
    float p[4][4];
#pragma unroll
    for (int reg = 0; reg < 4; ++reg) {
      const int r = wave * 16 + quad * 4 + reg;
      float val[4];
      float vmax = -1e30f;
#pragma unroll
      for (int j = 0; j < 4; ++j) {
        const int m = j * 16 + lrow;
        float s = acc[j][reg] * SCALE_F + s_bias[r - m + (WS - 1)];
        if (masked && (((r ^ m) & 32) != 0)) s -= 100.0f;
        val[j] = s;
        vmax = fmaxf(vmax, s);
      }
#pragma unroll
      for (int off = 1; off < 16; off <<= 1)
        vmax = fmaxf(vmax, __shfl_xor(vmax, off, 64));
      float sum = 0.f;
#pragma unroll
      for (int j = 0; j < 4; ++j) {
        val[j] = __expf(val[j] - vmax);
        sum += val[j];
      }
#pragma unroll
      for (int off = 1; off < 16; off <<= 1)
        sum += __shfl_xor(sum, off, 64);
      const float inv = 1.0f / sum;
#pragma unroll
      for (int j = 0; j < 4; ++j) p[reg][j] = val[j] * inv;
    }
    lds_barrier();  // (2) all K-fragment reads done

    // P (RNE bf16) into dead K-hi slab -- own rows only
#pragma unroll
    for (int reg = 0; reg < 4; ++reg) {
      const int r = wave * 16 + quad * 4 + reg;
#pragma unroll
      for (int j = 0; j < 4; ++j)
        s_k[0][r * LSTR + j * 16 + lrow] = rne1(p[reg][j]);
    }

    // X = P V (phi = own rows, per-wave DS ordering; V staged at (1))
    f32x4 xacc[4] = {z4, z4, z4, z4};
#pragma unroll
    for (int kh = 0; kh < 2; ++kh) {
      const int k0 = kh * 32 + quad * 8;
      const bf16x8 phi = *(const bf16x8*)(&s_k[0][(wave * 16 + lrow) * LSTR + k0]);
#pragma unroll
      for (int j = 0; j < 4; ++j) {
        const bf16x8 vhi = *(const bf16x8*)(&s_vt[(j * 16 + lrow) * LSTR + k0]);
        xacc[j] = __builtin_amdgcn_mfma_f32_16x16x32_bf16(phi, vhi, xacc[j], 0, 0, 0);
      }
    }
    lds_barrier();  // (3) all P writes visible

    // attn readback + coalesced dwordx4 store (attn == bf16(p), err ~2e-3)
    float* aw = attn_out + (size_t)idx * (WS * WS);
#pragma unroll
    for (int c = 0; c < 4; ++c) {
      const int row = c * 16 + srow;
      const u16x4 pb = *(const u16x4*)(&s_k[0][row * LSTR + scol]);
      f32x4 o = {bf2f(pb[0]), bf2f(pb[1]), bf2f(pb[2]), bf2f(pb[3])};
      __builtin_nontemporal_store(o, (f32x4*)(aw + (size_t)c * 1024 + t * 4));
    }
    lds_barrier();  // (4) all s_k reads done -> reuse as fp32 x buffer

    // x bounce through LDS (fp32, stride 68 = 272B rows, 16B-aligned)
    float* s_xf = (float*)&s_k[0][0];
#pragma unroll
    for (int reg = 0; reg < 4; ++reg) {
      const int r = wave * 16 + quad * 4 + reg;
#pragma unroll
      for (int j = 0; j < 4; ++j)
        s_xf[r * 68 + j * 16 + lrow] = xacc[j][reg];
    }
    lds_barrier();  // (5) x visible
#pragma unroll
    for (int c = 0; c < 4; ++c) {
      const int row = c * 16 + srow;
      const f32x4 xv = *(const f32x4*)(&s_xf[row * 68 + scol]);
      const int gr = (win * WS + row + SHIFT) & (WTOT - 1);
      __builtin_nontemporal_store(
          xv, (f32x4*)(xout + ((size_t)batch * WTOT + gr) * WS + scol));
    }
    lds_barrier();  // (6) protect next window's staging
  };

  // ---- ping-pong pipelined loop over 8 windows ----
  const int idx0 = blockIdx.x * WPB;
  float4 A[12], B[12];
  issue(idx0, A);
#pragma unroll 1
  for (int i = 0; i < WPB; i += 2) {
    issue(idx0 + i + 1, B);      // in flight during process(A)
    process(idx0 + i, A);
    if (i < WPB - 2) issue(idx0 + i + 2, A);  // in flight during process(B)
    process(idx0 + i + 1, B);
  }
}

extern "C" void kernel_launch(void* const* d_in, const int* in_sizes, int n_in,
                              void* d_out, int out_size, void* d_ws, size_t ws_size,
                              hipStream_t stream) {
  (void)in_sizes; (void)n_in; (void)out_size; (void)d_ws; (void)ws_size;
  const float* q = (const float*)d_in[0];
  const float* k = (const float*)d_in[1];
  const float* v = (const float*)d_in[2];
  const float* table = (const float*)d_in[3];
  float* xout = (float*)d_out;                               // (32, 8192, 64)
  float* attn = (float*)d_out + (size_t)32 * WTOT * WS;      // (4096, 64, 64)
  win_attn<<<dim3(NBLK), dim3(256), 0, stream>>>(q, k, v, table, xout, attn);
}